// Round 9
// baseline (556.317 us; speedup 1.0000x reference)
//
#include <hip/hip_runtime.h>
#include <math.h>

#define N_NODES 100000
#define N_EDGES 1600000
#define F_INN   256
#define HID     128
#define NCLS    47

#define SCAN_CHUNK 1024
#define N_SBLOCKS ((N_NODES + SCAN_CHUNK - 1) / SCAN_CHUNK)  // 98

typedef __attribute__((ext_vector_type(8))) short bf16x8;
typedef __attribute__((ext_vector_type(4))) float f32x4;

// ---------------- bf16 helpers (RNE) ----------------
__device__ __forceinline__ unsigned bf16pack(float a, float b) {
    unsigned ua = __float_as_uint(a), ub = __float_as_uint(b);
    ua = (ua + 0x7FFFu + ((ua >> 16) & 1u)) >> 16;
    ub = (ub + 0x7FFFu + ((ub >> 16) & 1u)) >> 16;
    return ua | (ub << 16);
}
__device__ __forceinline__ float2 bf16unpack(unsigned v) {
    return make_float2(__uint_as_float(v << 16), __uint_as_float(v & 0xFFFF0000u));
}
__device__ __forceinline__ float bf16tof(unsigned short u) {
    return __uint_as_float(((unsigned)u) << 16);
}

// ---------------- CSR build ----------------
__global__ void k_init(int* cnt) {
    int i = blockIdx.x * blockDim.x + threadIdx.x;
    if (i < N_NODES) cnt[i] = 0;
}

// count + record within-node rank (the atomic's return value)
__global__ void k_count(const int* __restrict__ dst, int* cnt,
                        unsigned char* __restrict__ rank) {
    int e = blockIdx.x * blockDim.x + threadIdx.x;
    if (e < N_EDGES) rank[e] = (unsigned char)atomicAdd(&cnt[dst[e]], 1);
}

// level-1: per-block (1024 counts) partial sums
__global__ __launch_bounds__(256) void k_scan_part(const int* __restrict__ cnt,
                                                   int* __restrict__ bsum) {
    int b = blockIdx.x, t = threadIdx.x;
    int base = b * SCAN_CHUNK;
    int local = 0;
#pragma unroll
    for (int u = 0; u < 4; u++) {
        int idx = base + u * 256 + t;
        if (idx < N_NODES) local += cnt[idx];
    }
#pragma unroll
    for (int off = 32; off >= 1; off >>= 1) local += __shfl_down(local, off, 64);
    __shared__ int red[4];
    if ((t & 63) == 0) red[t >> 6] = local;
    __syncthreads();
    if (t == 0) bsum[b] = red[0] + red[1] + red[2] + red[3];
}

// level-2: scan the 98 block sums (one small block)
__global__ void k_scan_top(const int* __restrict__ bsum, int* __restrict__ boff) {
    __shared__ int s[128];
    int t = threadIdx.x;
    int v = (t < N_SBLOCKS) ? bsum[t] : 0;
    s[t] = v;
    __syncthreads();
    for (int off = 1; off < 128; off <<= 1) {
        int u = (t >= off) ? s[t - off] : 0;
        __syncthreads();
        s[t] += u;
        __syncthreads();
    }
    if (t < N_SBLOCKS) boff[t] = s[t] - v;  // exclusive
}

// level-3: local scan per block + global offset -> rowptr, dinv
__global__ __launch_bounds__(256) void k_scan_final(const int* __restrict__ cnt,
                                                    const int* __restrict__ boff,
                                                    int* __restrict__ rowptr,
                                                    float* __restrict__ dinv) {
    __shared__ int tsum[256];
    int b = blockIdx.x, t = threadIdx.x;
    int base = b * SCAN_CHUNK + t * 4;
    int c[4];
    int local = 0;
#pragma unroll
    for (int u = 0; u < 4; u++) {
        int idx = base + u;
        c[u] = (idx < N_NODES) ? cnt[idx] : 0;
        local += c[u];
    }
    tsum[t] = local;
    __syncthreads();
    for (int off = 1; off < 256; off <<= 1) {
        int u = (t >= off) ? tsum[t - off] : 0;
        __syncthreads();
        tsum[t] += u;
        __syncthreads();
    }
    int run = boff[b] + tsum[t] - local;
#pragma unroll
    for (int u = 0; u < 4; u++) {
        int idx = base + u;
        if (idx < N_NODES) {
            rowptr[idx] = run;
            dinv[idx] = rsqrtf((float)c[u] + 1.0f);  // +1 self-loop
            run += c[u];
        }
    }
    if (b == 0 && t == 0) rowptr[N_NODES] = N_EDGES;
}

// atomic-free scatter using precomputed rank
__global__ void k_scatter(const int* __restrict__ src, const int* __restrict__ dst,
                          const int* __restrict__ rowptr,
                          const unsigned char* __restrict__ rank,
                          int* __restrict__ eidx) {
    int e = blockIdx.x * blockDim.x + threadIdx.x;
    if (e < N_EDGES) {
        int d = dst[e];
        eidx[rowptr[d] + (int)rank[e]] = src[e];
    }
}

// ---- prep: W1 (256x128 f32) -> MFMA-fragment-ordered bf16 ------------------
__global__ __launch_bounds__(256) void k_prep(const float* __restrict__ W1,
                                              uint4* __restrict__ Wf) {
    int g = blockIdx.x * blockDim.x + threadIdx.x;  // 0..4095
    if (g >= 4096) return;
    int l = g & 63;
    int kst = (g >> 6) & 7;
    int nt = g >> 9;
    int n = nt * 16 + (l & 15);
    int kb = kst * 32 + ((l >> 4) << 3);
    float v[8];
#pragma unroll
    for (int j = 0; j < 8; j++) v[j] = W1[(size_t)(kb + j) * HID + n];
    uint4 o;
    o.x = bf16pack(v[0], v[1]);
    o.y = bf16pack(v[2], v[3]);
    o.z = bf16pack(v[4], v[5]);
    o.w = bf16pack(v[6], v[7]);
    Wf[g] = o;
}

// ---------------- GEMM1 (MFMA): Ybc = bf16((X @ W1) * dinv[row]) ------------
// Output in CHUNKED layout: ybc[(c*N + row)*8 + slot] (u32), chunk c = 16 dims,
// slot s holds dims {2s, 2s+1} of the chunk.
__global__ __launch_bounds__(256) void k_gemm1(const float* __restrict__ X,
                                               const uint4* __restrict__ Wf,
                                               const float* __restrict__ dinv,
                                               unsigned* __restrict__ Ybc) {
    __shared__ __align__(16) unsigned short xs[128 * 32];
    int tid = threadIdx.x;
    int lane = tid & 63, w = tid >> 6;
    int wr = w >> 1, wc = w & 1;
    int row0 = blockIdx.x * 128;

    f32x4 acc[4][4];  // [fm][fn]
#pragma unroll
    for (int i = 0; i < 4; i++)
#pragma unroll
        for (int j = 0; j < 4; j++) acc[i][j] = (f32x4){0.f, 0.f, 0.f, 0.f};

    for (int ks = 0; ks < 8; ks++) {
        int k0 = ks * 32;
#pragma unroll
        for (int u = 0; u < 4; u++) {
            int slot = u * 256 + tid;          // 0..1023
            int r = slot >> 3, c4 = slot & 7;  // row, float4-slot
            int rr = min(row0 + r, N_NODES - 1);
            float4 v = *(const float4*)&X[(size_t)rr * F_INN + k0 + c4 * 4];
            uint2 p;
            p.x = bf16pack(v.x, v.y);
            p.y = bf16pack(v.z, v.w);
            *(uint2*)&xs[r * 32 + c4 * 4] = p;
        }
        bf16x8 bfr[4];
#pragma unroll
        for (int fn = 0; fn < 4; fn++) {
            uint4 t = Wf[((wc * 4 + fn) * 8 + ks) * 64 + lane];
            bfr[fn] = *(bf16x8*)&t;
        }
        __syncthreads();
        bf16x8 afr[4];
#pragma unroll
        for (int fm = 0; fm < 4; fm++) {
            int r = wr * 64 + fm * 16 + (lane & 15);
            afr[fm] = *(const bf16x8*)&xs[r * 32 + ((lane >> 4) << 3)];
        }
#pragma unroll
        for (int fm = 0; fm < 4; fm++)
#pragma unroll
            for (int fn = 0; fn < 4; fn++)
                acc[fm][fn] = __builtin_amdgcn_mfma_f32_16x16x32_bf16(
                    bfr[fn], afr[fm], acc[fm][fn], 0, 0, 0);
        __syncthreads();
    }
    // epilogue -> chunked layout
#pragma unroll
    for (int fm = 0; fm < 4; fm++) {
        int row = row0 + wr * 64 + fm * 16 + (lane & 15);
        if (row < N_NODES) {
            float s = dinv[row];
#pragma unroll
            for (int fn = 0; fn < 4; fn++) {
                int c = wc * 4 + fn;  // chunk = 16-dim column tile
                uint2 p;
                p.x = bf16pack(acc[fm][fn][0] * s, acc[fm][fn][1] * s);
                p.y = bf16pack(acc[fm][fn][2] * s, acc[fm][fn][3] * s);
                *(uint2*)&Ybc[((size_t)c * N_NODES + row) * 8 + ((lane >> 4) << 1)] = p;
            }
        }
    }
}

// --- gather1 (chunked, XCD-pinned): Hbc = bf16(relu(dinv*(y_i+sum y_j)+b1)) --
// grid = 8 chunks * 25000 blocks; chunk = blockIdx & 7 rides XCD round-robin.
// Wave = (node, chunk): 8 edge-groups x 8 dim-slots; shfl-xor group reduce.
__global__ __launch_bounds__(256) void k_gather1(const unsigned* __restrict__ Ybc,
                                                 const int* __restrict__ rowptr,
                                                 const int* __restrict__ eidx,
                                                 const float* __restrict__ dinv,
                                                 const float* __restrict__ b1,
                                                 unsigned* __restrict__ Hbc) {
    int tid = threadIdx.x;
    int chunk = blockIdx.x & 7;
    int d = (blockIdx.x >> 3) * 4 + (tid >> 6);
    if (d >= N_NODES) return;
    int lane = tid & 63, g = lane >> 3, l = lane & 7;
    const unsigned* yc = Ybc + (size_t)chunk * N_NODES * 8;

    float ax = 0.f, ay = 0.f;
    if (g == 0) {  // self-loop
        float2 t = bf16unpack(yc[(size_t)d * 8 + l]);
        ax = t.x; ay = t.y;
    }
    int beg = rowptr[d], end = rowptr[d + 1];
    int e = beg + g;
    for (; e + 8 < end; e += 16) {  // 2-deep pipeline
        int j0 = __builtin_nontemporal_load(&eidx[e]);
        int j1 = __builtin_nontemporal_load(&eidx[e + 8]);
        unsigned v0 = yc[(size_t)j0 * 8 + l];
        unsigned v1 = yc[(size_t)j1 * 8 + l];
        float2 a = bf16unpack(v0), b = bf16unpack(v1);
        ax += a.x + b.x; ay += a.y + b.y;
    }
    if (e < end) {
        int j0 = __builtin_nontemporal_load(&eidx[e]);
        float2 a = bf16unpack(yc[(size_t)j0 * 8 + l]);
        ax += a.x; ay += a.y;
    }
    // reduce across the 8 edge-groups
    ax += __shfl_xor(ax, 8, 64);  ay += __shfl_xor(ay, 8, 64);
    ax += __shfl_xor(ax, 16, 64); ay += __shfl_xor(ay, 16, 64);
    ax += __shfl_xor(ax, 32, 64); ay += __shfl_xor(ay, 32, 64);
    if (g == 0) {
        float s = dinv[d];
        float2 b = ((const float2*)b1)[chunk * 8 + l];
        float ox = fmaxf(ax * s + b.x, 0.f);
        float oy = fmaxf(ay * s + b.y, 0.f);
        Hbc[((size_t)chunk * N_NODES + d) * 8 + l] = bf16pack(ox, oy);
    }
}

// ------------- GEMM2: Y2b = bf16((H @ W2) * dinv[row]), H in chunked layout -
__global__ __launch_bounds__(256) void k_gemm2(const unsigned* __restrict__ Hbc,
                                               const float* __restrict__ W2,
                                               const float* __restrict__ dinv,
                                               unsigned short* __restrict__ Y2b) {
    __shared__ __align__(16) float ws[128][48];
    int tid = threadIdx.x;
    for (int idx = tid; idx < 128 * 48; idx += 256) {
        int k = idx / 48, c = idx - k * 48;
        ws[k][c] = (c < NCLS) ? W2[k * NCLS + c] : 0.f;
    }
    __syncthreads();
    int row = blockIdx.x * 256 + tid;
    if (row >= N_NODES) return;
    float4 acc[12];
#pragma unroll
    for (int i = 0; i < 12; i++) acc[i] = make_float4(0.f, 0.f, 0.f, 0.f);
#pragma unroll
    for (int c = 0; c < 8; c++) {
        const uint4* hc = (const uint4*)(Hbc + ((size_t)c * N_NODES + row) * 8);
        uint4 A = hc[0], B = hc[1];
        unsigned sv[8] = {A.x, A.y, A.z, A.w, B.x, B.y, B.z, B.w};
#pragma unroll
        for (int s = 0; s < 8; s++) {
            float2 f = bf16unpack(sv[s]);
            int k = c * 16 + 2 * s;
#pragma unroll
            for (int cc = 0; cc < 12; cc++) {
                float4 w0 = *(const float4*)&ws[k][cc * 4];
                float4 w1 = *(const float4*)&ws[k + 1][cc * 4];
                acc[cc].x += f.x * w0.x + f.y * w1.x;
                acc[cc].y += f.x * w0.y + f.y * w1.y;
                acc[cc].z += f.x * w0.z + f.y * w1.z;
                acc[cc].w += f.x * w0.w + f.y * w1.w;
            }
        }
    }
    float s = dinv[row];
#pragma unroll
    for (int c = 0; c < 12; c++) {
        uint2 o;
        o.x = bf16pack(acc[c].x * s, acc[c].y * s);
        o.y = bf16pack(acc[c].z * s, acc[c].w * s);
        *(uint2*)((char*)Y2b + ((size_t)row * 64 + c * 4) * 2) = o;
    }
}

// --- gather2 + fused log_softmax, unroll 16 ---------------------------------
__global__ __launch_bounds__(256) void k_gather2(const unsigned short* __restrict__ Y2b,
                                                 const int* __restrict__ rowptr,
                                                 const int* __restrict__ eidx,
                                                 const float* __restrict__ dinv,
                                                 const float* __restrict__ b2,
                                                 float* __restrict__ Out) {
    int wave = (blockIdx.x * blockDim.x + threadIdx.x) >> 6;
    int lane = threadIdx.x & 63;
    if (wave >= N_NODES) return;
    bool act = lane < NCLS;
    float acc = bf16tof(Y2b[(size_t)wave * 64 + lane]);  // lanes>=47 read pad (gated later)
    int beg = rowptr[wave], end = rowptr[wave + 1];
    int e = beg;
    for (; e + 15 < end; e += 16) {
        int j[16];
#pragma unroll
        for (int u = 0; u < 16; u++) j[u] = __builtin_nontemporal_load(&eidx[e + u]);
        float v[16];
#pragma unroll
        for (int u = 0; u < 16; u++) v[u] = bf16tof(Y2b[(size_t)j[u] * 64 + lane]);
        float s0 = 0.f;
#pragma unroll
        for (int u = 0; u < 16; u++) s0 += v[u];
        acc += s0;
    }
    for (; e + 3 < end; e += 4) {
        int j0 = eidx[e], j1 = eidx[e + 1], j2 = eidx[e + 2], j3 = eidx[e + 3];
        float v0 = bf16tof(Y2b[(size_t)j0 * 64 + lane]);
        float v1 = bf16tof(Y2b[(size_t)j1 * 64 + lane]);
        float v2 = bf16tof(Y2b[(size_t)j2 * 64 + lane]);
        float v3 = bf16tof(Y2b[(size_t)j3 * 64 + lane]);
        acc += (v0 + v1) + (v2 + v3);
    }
    for (; e < end; e++) {
        acc += bf16tof(Y2b[(size_t)eidx[e] * 64 + lane]);
    }
    float v = act ? (acc * dinv[wave] + b2[lane]) : -INFINITY;
    float m = v;
#pragma unroll
    for (int off = 32; off >= 1; off >>= 1) m = fmaxf(m, __shfl_xor(m, off, 64));
    float ex = act ? __expf(v - m) : 0.f;
    float ssum = ex;
#pragma unroll
    for (int off = 32; off >= 1; off >>= 1) ssum += __shfl_xor(ssum, off, 64);
    float l = __logf(ssum);
    if (act) Out[(size_t)wave * NCLS + lane] = v - m - l;
}

extern "C" void kernel_launch(void* const* d_in, const int* in_sizes, int n_in,
                              void* d_out, int out_size, void* d_ws, size_t ws_size,
                              hipStream_t stream) {
    const float* x   = (const float*)d_in[0];
    const int*   ei  = (const int*)d_in[1];
    const float* W1  = (const float*)d_in[2];
    const float* b1  = (const float*)d_in[3];
    const float* W2  = (const float*)d_in[4];
    const float* b2  = (const float*)d_in[5];
    float* out = (float*)d_out;

    const int* src = ei;             // edge_index[0]
    const int* dst = ei + N_EDGES;   // edge_index[1]

    char* ws = (char*)d_ws;
    unsigned*       ybc  = (unsigned*)      (ws + 0);          // chunked, N*64 u32 (25.6 MB)
    unsigned*       hbc  = (unsigned*)      (ws + 25600000);   // chunked, N*64 u32 (25.6 MB)
    unsigned short* y2b  = (unsigned short*)(ws + 51200000);   // N*64 u16  (12.8 MB)
    float*          dinv = (float*)         (ws + 64000000);   // N f32
    int*            cnt  = (int*)           (ws + 64400000);   // N int
    int*            rowptr=(int*)           (ws + 64800000);   // N+1 int
    int*            eidx = (int*)           (ws + 65200016);   // E int (6.4 MB)
    int*            bsum = (int*)           (ws + 71600016);   // 98 int
    int*            boff = (int*)           (ws + 71601040);   // 98 int
    unsigned char*  rank = (unsigned char*) (ws + 71602064);   // E u8 (1.6 MB)
    uint4*          wfrag= (uint4*)         (ws + 73202064);   // 64 KB

    // CSR build
    k_init<<<(N_NODES + 255) / 256, 256, 0, stream>>>(cnt);
    k_count<<<(N_EDGES + 255) / 256, 256, 0, stream>>>(dst, cnt, rank);
    k_scan_part<<<N_SBLOCKS, 256, 0, stream>>>(cnt, bsum);
    k_scan_top<<<1, 128, 0, stream>>>(bsum, boff);
    k_scan_final<<<N_SBLOCKS, 256, 0, stream>>>(cnt, boff, rowptr, dinv);
    k_scatter<<<(N_EDGES + 255) / 256, 256, 0, stream>>>(src, dst, rowptr, rank, eidx);

    // W1 -> fragment-ordered bf16
    k_prep<<<16, 256, 0, stream>>>(W1, wfrag);

    // layer 1
    k_gemm1<<<(N_NODES + 127) / 128, 256, 0, stream>>>(x, wfrag, dinv, ybc);
    // chunked gather: 8 chunks x ceil(N/4) node-blocks, chunk = bid & 7
    k_gather1<<<8 * ((N_NODES + 3) / 4), 256, 0, stream>>>(ybc, rowptr, eidx, dinv, b1, hbc);

    // layer 2
    k_gemm2<<<(N_NODES + 255) / 256, 256, 0, stream>>>(hbc, W2, dinv, y2b);
    k_gather2<<<(N_NODES * 64 + 255) / 256, 256, 0, stream>>>(y2b, rowptr, eidx, dinv, b2, out);
}